// Round 7
// baseline (175.057 us; speedup 1.0000x reference)
//
#include <hip/hip_runtime.h>
#include <hip/hip_bf16.h>

#define N_ROWS 300000
#define FIN    128
#define HDIM   64
#define ODIM   32
#define KREL   5
#define BR     64
#define NTILES ((N_ROWS + BR - 1) / BR + KREL)   // 4693
#define NB     (NTILES * BR)
#define TPB    4
#define MAXCHUNK ((NTILES + TPB - 1) / TPB + KREL)

typedef __attribute__((ext_vector_type(8))) short bf8_t;   // 8 bf16 = 4 VGPR
typedef __attribute__((ext_vector_type(4))) float f32x4;
typedef __attribute__((ext_vector_type(4))) unsigned int u32x4;

static __device__ __forceinline__ unsigned pk2(float lo, float hi) {
  __hip_bfloat162 h = __float22bfloat162_rn(make_float2(lo, hi));
  return *reinterpret_cast<unsigned*>(&h);
}

static __device__ __forceinline__ bf8_t cvt8(float4 a, float4 b) {
  u32x4 u;
  u.x = pk2(a.x, a.y);
  u.y = pk2(a.z, a.w);
  u.z = pk2(b.x, b.y);
  u.w = pk2(b.z, b.w);
  return __builtin_bit_cast(bf8_t, u);
}

static __device__ __forceinline__ void stbf4_pk(void* base, int byte, float4 v) {
  unsigned long long p = (unsigned long long)pk2(v.x, v.y)
                       | ((unsigned long long)pk2(v.z, v.w) << 32);
  *(unsigned long long*)((char*)base + byte) = p;
}

static __device__ __forceinline__ bf8_t lds_load16(const void* base, int byte) {
  return *(const bf8_t*)((const char*)base + byte);
}

// ---------------- bucketing ----------------

__global__ void hist_kernel(const int* __restrict__ r, int* __restrict__ cnt) {
  __shared__ int lc[KREL];
  int tid = threadIdx.x;
  if (tid < KREL) lc[tid] = 0;
  __syncthreads();
  int i = blockIdx.x * blockDim.x + tid;
  if (i < N_ROWS) atomicAdd(&lc[r[i]], 1);
  __syncthreads();
  if (tid < KREL && lc[tid]) atomicAdd(&cnt[tid], lc[tid]);
}

__global__ void offs_kernel(const int* __restrict__ cnt, int* __restrict__ aoff,
                            int* __restrict__ cursor, int* __restrict__ cb,
                            int* __restrict__ ts) {
  int off = 0;
  for (int k = 0; k < KREL; ++k) {
    aoff[k] = off;
    cursor[k] = off;
    off += ((cnt[k] + BR - 1) / BR) * BR;
  }
  aoff[KREL] = off;
  // relation-aware chunk table: chunks never cross a relation boundary
  int cc = 0;
  for (int k = 0; k < KREL; ++k) {
    ts[k] = aoff[k] / BR;
    int ntk = (aoff[k + 1] - aoff[k]) / BR;
    cb[k] = cc;
    cc += (ntk + TPB - 1) / TPB;
  }
  cb[KREL] = cc;
  ts[KREL] = aoff[KREL] / BR;
}

__global__ void scat_kernel(const int* __restrict__ r, const float* __restrict__ c,
                            int* __restrict__ bucket, float* __restrict__ cbv,
                            int* __restrict__ cursor) {
  __shared__ int lc[KREL];
  __shared__ int base[KREL];
  int tid = threadIdx.x;
  if (tid < KREL) lc[tid] = 0;
  __syncthreads();
  int i = blockIdx.x * blockDim.x + tid;
  int k = 0, lr = 0;
  float cv = 0.f;
  if (i < N_ROWS) { k = r[i]; lr = atomicAdd(&lc[k], 1); cv = c[i]; }
  __syncthreads();
  if (tid < KREL) base[tid] = lc[tid] ? atomicAdd(&cursor[tid], lc[tid]) : 0;
  __syncthreads();
  if (i < N_ROWS) {
    int pos = base[k] + lr;
    bucket[pos] = i;
    cbv[pos]    = cv;
  }
}

// ---------------- main fused kernel ----------------
// One block = one side x one relation-homogeneous chunk of <=TPB tiles.
// 256 threads = 4 waves, each owns 16 rows/tile. NO LDS for X: A-fragments
// gathered straight from global into registers (double-buffered across tiles,
// split-issued around the MFMA blocks). LDS = 16KB W + 8KB H -> with
// launch_bounds(256,4): 4 blocks/CU = 16 waves/CU (~50% occupancy).
// No barrier in the steady-state loop.

__global__ __launch_bounds__(256, 4) void gcn_main(
    const float* __restrict__ user, const float* __restrict__ item,
    const float* __restrict__ Wu, const float* __restrict__ bu,
    const float* __restrict__ Wv, const float* __restrict__ bv,
    const float* __restrict__ Wl, const float* __restrict__ bl,
    const int* __restrict__ bucket, const float* __restrict__ cbv,
    const int* __restrict__ cb, const int* __restrict__ ts,
    float* __restrict__ out)
{
  __shared__ __align__(16) unsigned short sW[HDIM * FIN];   // 16 KB bf16, swizzled
  __shared__ __align__(16) unsigned short sH[4 * 1024];     // 2 KB per wave

  const int tid  = threadIdx.x;
  const int side = blockIdx.x & 1;            // 0: item->u_out, 1: user->v_out
  const int cid  = blockIdx.x >> 1;
  if (cid >= cb[KREL]) return;

  const int rel = (cid >= cb[1]) + (cid >= cb[2]) + (cid >= cb[3]) + (cid >= cb[4]);
  const int t_begin = ts[rel] + (cid - cb[rel]) * TPB;
  const int t_end   = (t_begin + TPB < ts[rel + 1]) ? t_begin + TPB : ts[rel + 1];

  const float* X  = side ? user : item;
  const float* Wk = side ? Wv : Wu;
  const float* bk = side ? bv : bu;

  const int lane = tid & 63;
  const int wid  = tid >> 6;        // wave 0..3; owns tile rows [wid*16, wid*16+16)
  const int lrow = lane & 15;
  const int lkg  = lane >> 4;

  // stage relation weights -> bf16 LDS, XOR-swizzled (row stride 256 B)
  {
    const float4* w4 = (const float4*)(Wk + (size_t)rel * HDIM * FIN);
    #pragma unroll
    for (int it = 0; it < 8; ++it) {
      int f4  = it * 256 + tid;
      int row = f4 >> 5;
      int cc  = f4 & 31;
      int byte = (row * 256 + cc * 8) ^ ((row & 7) << 4);
      stbf4_pk(sW, byte, w4[f4]);
    }
  }

  // layer-2 weights + biases in registers
  bf8_t wl[2][2];
  #pragma unroll
  for (int n2 = 0; n2 < 2; ++n2)
    #pragma unroll
    for (int k2 = 0; k2 < 2; ++k2) {
      const float* p = Wl + (size_t)(n2 * 16 + lrow) * HDIM + k2 * 32 + lkg * 8;
      wl[n2][k2] = cvt8(*(const float4*)p, *(const float4*)(p + 4));
    }
  const float blv0 = bl[lrow];
  const float blv1 = bl[16 + lrow];
  float bfrag[4];
  #pragma unroll
  for (int n = 0; n < 4; ++n) bfrag[n] = bk[rel * HDIM + n * 16 + lrow];

  // per-lane A-row index: lane(lrow,lkg) gathers row lrow of the wave's 16
  const int rowoff = wid * 16 + lrow;

  // prologue: idx + A-data for first tile; idx for second
  int idx0 = bucket[t_begin * BR + rowoff];
  {
    int tB = (t_begin + 1 < t_end) ? t_begin + 1 : t_begin;
    // (idxN loaded below, after ldA issue, to keep the gather chain tight)
  }
  float4 ldA[8];
  {
    const float* p = X + (size_t)(idx0 < 0 ? 0 : idx0) * FIN + lkg * 8;
    #pragma unroll
    for (int kc = 0; kc < 4; ++kc) {
      ldA[2 * kc]     = *(const float4*)(p + kc * 32);
      ldA[2 * kc + 1] = *(const float4*)(p + kc * 32 + 4);
    }
  }
  int idxN;
  {
    int tB = (t_begin + 1 < t_end) ? t_begin + 1 : t_begin;
    idxN = bucket[tB * BR + rowoff];
  }

  __syncthreads();   // sW visible; ONLY barrier in the kernel

  unsigned short* myH = sH + wid * 1024;   // 2048 bytes: [16 rows][64 cols] bf16 swizzled

  for (int t = t_begin; t < t_end; ++t) {
    const bool more = (t + 1 < t_end);

    // idx prefetch for t+2
    const int tN2 = (t + 2 < t_end) ? t + 2 : t_end - 1;
    int idxN2 = bucket[tN2 * BR + rowoff];

    // epilogue inputs for t (coalesced)
    const int erow = t * BR + wid * 16 + lkg * 4;
    int4   idxQ4 = *(const int4*)(bucket + erow);
    float4 cQ4   = *(const float4*)(cbv + erow);
    int   idxQ[4] = {idxQ4.x, idxQ4.y, idxQ4.z, idxQ4.w};
    float cQ[4]   = {cQ4.x, cQ4.y, cQ4.z, cQ4.w};

    // issue-early: first half of tile t+1's A-gather (kc 0,1)
    const float* pn = X + (size_t)(idxN < 0 ? 0 : idxN) * FIN + lkg * 8;
    float4 ldB[8];
    if (more) {
      ldB[0] = *(const float4*)(pn + 0);
      ldB[1] = *(const float4*)(pn + 4);
      ldB[2] = *(const float4*)(pn + 32);
      ldB[3] = *(const float4*)(pn + 36);
    }
    __builtin_amdgcn_sched_barrier(0);

    // ---- layer 1, kc = 0,1 ----
    f32x4 acc[4];
    #pragma unroll
    for (int n = 0; n < 4; ++n) acc[n] = f32x4{0.f, 0.f, 0.f, 0.f};
    #pragma unroll
    for (int kc = 0; kc < 2; ++kc) {
      bf8_t au = cvt8(*(float4*)&ldA[2 * kc], *(float4*)&ldA[2 * kc + 1]);
      const int kb = (kc * 32 + lkg * 8) * 2;
      #pragma unroll
      for (int n = 0; n < 4; ++n) {
        int brow = n * 16 + lrow;
        int bx   = (brow * 256 + kb) ^ ((brow & 7) << 4);
        acc[n] = __builtin_amdgcn_mfma_f32_16x16x32_bf16(au, lds_load16(sW, bx), acc[n], 0, 0, 0);
      }
    }
    __builtin_amdgcn_sched_barrier(0);

    // issue second half of t+1's A-gather (kc 2,3) — ldA[0..3] now dead
    if (more) {
      ldB[4] = *(const float4*)(pn + 64);
      ldB[5] = *(const float4*)(pn + 68);
      ldB[6] = *(const float4*)(pn + 96);
      ldB[7] = *(const float4*)(pn + 100);
    }
    __builtin_amdgcn_sched_barrier(0);

    // ---- layer 1, kc = 2,3 ----
    #pragma unroll
    for (int kc = 2; kc < 4; ++kc) {
      bf8_t au = cvt8(*(float4*)&ldA[2 * kc], *(float4*)&ldA[2 * kc + 1]);
      const int kb = (kc * 32 + lkg * 8) * 2;
      #pragma unroll
      for (int n = 0; n < 4; ++n) {
        int brow = n * 16 + lrow;
        int bx   = (brow * 256 + kb) ^ ((brow & 7) << 4);
        acc[n] = __builtin_amdgcn_mfma_f32_16x16x32_bf16(au, lds_load16(sW, bx), acc[n], 0, 0, 0);
      }
    }

    // epilogue 1: H = relu(c*(acc+b)) -> this wave's private 2KB LDS
    #pragma unroll
    for (int n = 0; n < 4; ++n) {
      int hcol = n * 16 + lrow;
      #pragma unroll
      for (int q = 0; q < 4; ++q) {
        int rr   = lkg * 4 + q;      // local row 0..15
        int byte = (rr * 128 + hcol * 2) ^ ((rr & 7) << 4);
        float hv = fmaxf(cQ[q] * (acc[n][q] + bfrag[n]), 0.f);
        *(unsigned short*)((char*)myH + byte) = (unsigned short)(pk2(hv, hv) & 0xFFFFu);
      }
    }

    // ---- layer 2: [16 rows] x [32 o], K = 64 (same-wave LDS RAW; no barrier) ----
    f32x4 acc2[2];
    acc2[0] = f32x4{0.f, 0.f, 0.f, 0.f};
    acc2[1] = f32x4{0.f, 0.f, 0.f, 0.f};
    #pragma unroll
    for (int k2 = 0; k2 < 2; ++k2) {
      const int kb = (k2 * 32 + lkg * 8) * 2;
      const int ax = (lrow * 128 + kb) ^ ((lrow & 7) << 4);
      bf8_t a2 = lds_load16(myH, ax);
      #pragma unroll
      for (int n2 = 0; n2 < 2; ++n2)
        acc2[n2] = __builtin_amdgcn_mfma_f32_16x16x32_bf16(a2, wl[n2][k2], acc2[n2], 0, 0, 0);
    }

    // epilogue 2: out = relu(acc2 + bl), scattered row stores (retire async)
    const size_t obase = (size_t)side * N_ROWS * ODIM;
    #pragma unroll
    for (int n2 = 0; n2 < 2; ++n2) {
      int col  = n2 * 16 + lrow;
      float bb = (n2 == 0) ? blv0 : blv1;
      #pragma unroll
      for (int q = 0; q < 4; ++q) {
        int idx = idxQ[q];
        if (idx >= 0)
          out[obase + (size_t)idx * ODIM + col] = fmaxf(acc2[n2][q] + bb, 0.f);
      }
    }

    // rotate double-buffered A registers + index prefetch
    if (more) {
      #pragma unroll
      for (int i = 0; i < 8; ++i) ldA[i] = ldB[i];
    }
    idxN = idxN2;
  }
}

extern "C" void kernel_launch(void* const* d_in, const int* in_sizes, int n_in,
                              void* d_out, int out_size, void* d_ws, size_t ws_size,
                              hipStream_t stream) {
  const float* user = (const float*)d_in[0];
  const float* item = (const float*)d_in[1];
  const int*   r    = (const int*)d_in[2];
  const float* c    = (const float*)d_in[3];
  const float* Wu   = (const float*)d_in[4];
  const float* bu   = (const float*)d_in[5];
  const float* Wv   = (const float*)d_in[6];
  const float* bv   = (const float*)d_in[7];
  const float* Wl   = (const float*)d_in[8];
  const float* bl   = (const float*)d_in[9];
  float* out = (float*)d_out;

  int*   bucket = (int*)d_ws;            // NB ints
  float* cbv    = (float*)(bucket + NB); // NB floats
  int*   cnt    = (int*)(cbv + NB);      // KREL
  int*   cursor = cnt + KREL;            // KREL
  int*   aoff   = cursor + KREL;         // KREL+1
  int*   cb     = aoff + KREL + 1;       // KREL+1 (chunk bases per relation)
  int*   tsarr  = cb + KREL + 1;         // KREL+1 (tile starts per relation)

  hipMemsetAsync(bucket, 0xFF, (size_t)NB * sizeof(int), stream);
  hipMemsetAsync(cbv, 0, (size_t)NB * sizeof(float), stream);
  hipMemsetAsync(cnt, 0, KREL * sizeof(int), stream);

  const int nthr = 256;
  hist_kernel<<<(N_ROWS + nthr - 1) / nthr, nthr, 0, stream>>>(r, cnt);
  offs_kernel<<<1, 1, 0, stream>>>(cnt, aoff, cursor, cb, tsarr);
  scat_kernel<<<(N_ROWS + nthr - 1) / nthr, nthr, 0, stream>>>(r, c, bucket, cbv, cursor);
  gcn_main<<<2 * MAXCHUNK, 256, 0, stream>>>(user, item, Wu, bu, Wv, bv, Wl, bl,
                                             bucket, cbv, cb, tsarr, out);
}

// Round 8
// 117.512 us; speedup vs baseline: 1.4897x; 1.4897x over previous
//
#include <hip/hip_runtime.h>
#include <hip/hip_bf16.h>

#define N_ROWS 300000
#define FIN    128
#define HDIM   64
#define ODIM   32
#define KREL   5
#define BR     64
#define NTILES ((N_ROWS + BR - 1) / BR + KREL)   // 4693
#define NB     (NTILES * BR)
#define TPB    8
#define MAXCHUNK ((NTILES + TPB - 1) / TPB + KREL)
#define NBH    ((N_ROWS + 255) / 256)            // 1172 histogram blocks

typedef __attribute__((ext_vector_type(8))) short bf8_t;   // 8 bf16 = 4 VGPR
typedef __attribute__((ext_vector_type(4))) float f32x4;
typedef __attribute__((ext_vector_type(4))) unsigned int u32x4;

static __device__ __forceinline__ unsigned pk2(float lo, float hi) {
  __hip_bfloat162 h = __float22bfloat162_rn(make_float2(lo, hi));
  return *reinterpret_cast<unsigned*>(&h);
}

static __device__ __forceinline__ bf8_t cvt8(float4 a, float4 b) {
  u32x4 u;
  u.x = pk2(a.x, a.y);
  u.y = pk2(a.z, a.w);
  u.z = pk2(b.x, b.y);
  u.w = pk2(b.z, b.w);
  return __builtin_bit_cast(bf8_t, u);
}

static __device__ __forceinline__ void stbf4_pk(void* base, int byte, float4 v) {
  unsigned long long p = (unsigned long long)pk2(v.x, v.y)
                       | ((unsigned long long)pk2(v.z, v.w) << 32);
  *(unsigned long long*)((char*)base + byte) = p;
}

static __device__ __forceinline__ bf8_t lds_load16(const void* base, int byte) {
  return *(const bf8_t*)((const char*)base + byte);
}

// ---------------- stable counting sort by relation ----------------
// Pass 1: per-block histograms
__global__ void blockhist_kernel(const int* __restrict__ r, int* __restrict__ blockcnt) {
  __shared__ int lc[KREL];
  int tid = threadIdx.x;
  if (tid < KREL) lc[tid] = 0;
  __syncthreads();
  int i = blockIdx.x * 256 + tid;
  if (i < N_ROWS) atomicAdd(&lc[r[i]], 1);
  __syncthreads();
  if (tid < KREL) blockcnt[blockIdx.x * KREL + tid] = lc[tid];
}

// Pass 2: one block, 5 waves; wave k scans relation k's block counts.
__global__ void scan_kernel(const int* __restrict__ blockcnt, int* __restrict__ base,
                            int* __restrict__ aoff, int* __restrict__ cb,
                            int* __restrict__ ts) {
  __shared__ int totals[KREL];
  __shared__ int aoff_s[KREL + 1];
  const int tid  = threadIdx.x;
  const int k    = tid >> 6;
  const int lane = tid & 63;

  // phase 1: per-relation totals
  if (k < KREL) {
    int part = 0;
    for (int b = lane; b < NBH; b += 64) part += blockcnt[b * KREL + k];
    #pragma unroll
    for (int off = 1; off < 64; off <<= 1) part += __shfl_xor(part, off);
    if (lane == 0) totals[k] = part;
  }
  __syncthreads();

  // phase 2: aoff + chunk tables (thread 0)
  if (tid == 0) {
    int off = 0, cc = 0;
    for (int kk = 0; kk < KREL; ++kk) {
      aoff[kk] = off; aoff_s[kk] = off;
      off += ((totals[kk] + BR - 1) / BR) * BR;
    }
    aoff[KREL] = off; aoff_s[KREL] = off;
    for (int kk = 0; kk < KREL; ++kk) {
      ts[kk] = aoff_s[kk] / BR;
      int ntk = (aoff_s[kk + 1] - aoff_s[kk]) / BR;
      cb[kk] = cc;
      cc += (ntk + TPB - 1) / TPB;
    }
    cb[KREL] = cc;
    ts[KREL] = aoff_s[KREL] / BR;
  }
  __syncthreads();

  // phase 3: exclusive prefix over blocks for each relation
  if (k < KREL) {
    int running = aoff_s[k];
    for (int b0 = 0; b0 < NBH; b0 += 64) {
      int b = b0 + lane;
      int v = (b < NBH) ? blockcnt[b * KREL + k] : 0;
      int s = v;
      #pragma unroll
      for (int off = 1; off < 64; off <<= 1) {
        int t = __shfl_up(s, off);
        if (lane >= off) s += t;
      }
      if (b < NBH) base[b * KREL + k] = running + s - v;
      running += __shfl(s, 63);
    }
  }
}

// Pass 3: stable scatter (block/wave/lane order preserves ascending row index)
__global__ void scatter2_kernel(const int* __restrict__ r, const float* __restrict__ c,
                                const int* __restrict__ base, int* __restrict__ bucket,
                                float* __restrict__ cbv) {
  __shared__ int wcnt[4][KREL];
  __shared__ int wbase[4][KREL];
  const int tid  = threadIdx.x;
  const int wid  = tid >> 6;
  const int lane = tid & 63;
  const int i = blockIdx.x * 256 + tid;
  int k = -1; float cv = 0.f;
  if (i < N_ROWS) { k = r[i]; cv = c[i]; }

  int rank = 0;
  #pragma unroll
  for (int kk = 0; kk < KREL; ++kk) {
    unsigned long long m = __ballot(k == kk);
    if (lane == 0) wcnt[wid][kk] = __popcll(m);
    if (k == kk) rank = __popcll(m & ((1ull << lane) - 1ull));
  }
  __syncthreads();
  if (tid < KREL) {
    int b = base[blockIdx.x * KREL + tid];
    #pragma unroll
    for (int w = 0; w < 4; ++w) { wbase[w][tid] = b; b += wcnt[w][tid]; }
  }
  __syncthreads();
  if (i >= 0 && i < N_ROWS) {
    int pos = wbase[wid][k] + rank;
    bucket[pos] = i;
    cbv[pos]    = cv;
  }
}

// ---------------- main fused kernel (identical to R6's validated kernel) ----------------
// One block = one side x one relation-homogeneous chunk of <=TPB tiles.
// 256 threads = 4 waves. W staged ONCE per block (only barrier). X is
// wave-private: each wave gathers, converts, and ds_writes its own 16 rows,
// double-buffered; same-wave vmcnt/lgkmcnt ordering -> NO barrier in loop.
// LDS: 16KB W + 2x16KB X = 48KB -> 3 blocks/CU = 12 independent wave-streams.
// Buckets are now SORTED ascending -> gathers are near-streaming.

__global__ __launch_bounds__(256, 3) void gcn_main(
    const float* __restrict__ user, const float* __restrict__ item,
    const float* __restrict__ Wu, const float* __restrict__ bu,
    const float* __restrict__ Wv, const float* __restrict__ bv,
    const float* __restrict__ Wl, const float* __restrict__ bl,
    const int* __restrict__ bucket, const float* __restrict__ cbv,
    const int* __restrict__ cb, const int* __restrict__ ts,
    float* __restrict__ out)
{
  __shared__ __align__(16) unsigned short sW[HDIM * FIN];      // 16 KB bf16, swizzled
  __shared__ __align__(16) unsigned short sX[2][BR * FIN];     // 2 x 16 KB bf16

  const int tid  = threadIdx.x;
  const int side = blockIdx.x & 1;            // 0: item->u_out, 1: user->v_out
  const int cid  = blockIdx.x >> 1;
  if (cid >= cb[KREL]) return;

  const int rel = (cid >= cb[1]) + (cid >= cb[2]) + (cid >= cb[3]) + (cid >= cb[4]);
  const int t_begin = ts[rel] + (cid - cb[rel]) * TPB;
  const int t_end   = (t_begin + TPB < ts[rel + 1]) ? t_begin + TPB : ts[rel + 1];

  const float* X  = side ? user : item;
  const float* Wk = side ? Wv : Wu;
  const float* bk = side ? bv : bu;

  const int lane = tid & 63;
  const int wid  = tid >> 6;        // wave 0..3; owns tile rows [wid*16, wid*16+16)
  const int lrow = lane & 15;
  const int lkg  = lane >> 4;
  const int sh   = lane >> 5;       // staging: which row of the lane's pair
  const int c4   = lane & 31;       // staging: float4 column (global col = c4*4)

  // stage relation weights -> bf16 LDS, XOR-swizzled (row stride 256 B)
  {
    const float4* w4 = (const float4*)(Wk + (size_t)rel * HDIM * FIN);
    #pragma unroll
    for (int it = 0; it < 8; ++it) {
      int f4  = it * 256 + tid;
      int row = f4 >> 5;
      int cc  = f4 & 31;
      int byte = (row * 256 + cc * 8) ^ ((row & 7) << 4);
      stbf4_pk(sW, byte, w4[f4]);
    }
  }

  // layer-2 weights + biases in registers
  bf8_t wl[2][2];
  #pragma unroll
  for (int n2 = 0; n2 < 2; ++n2)
    #pragma unroll
    for (int k2 = 0; k2 < 2; ++k2) {
      const float* p = Wl + (size_t)(n2 * 16 + lrow) * HDIM + k2 * 32 + lkg * 8;
      wl[n2][k2] = cvt8(*(const float4*)p, *(const float4*)(p + 4));
    }
  const float blv0 = bl[lrow];
  const float blv1 = bl[16 + lrow];
  float bfrag[4];
  #pragma unroll
  for (int n = 0; n < 4; ++n) bfrag[n] = bk[rel * HDIM + n * 16 + lrow];

  // wave-private index prefetch: lane covers rows wid*16 + it*2 + sh, it=0..7
  int idxA[8], idxB[8];
  {
    const int tB = (t_begin + 1 < t_end) ? t_begin + 1 : t_begin;
    #pragma unroll
    for (int it = 0; it < 8; ++it) {
      idxA[it] = bucket[t_begin * BR + wid * 16 + it * 2 + sh];
      idxB[it] = bucket[tB * BR + wid * 16 + it * 2 + sh];
    }
  }

  // prologue: stage first tile into this wave's region of sX[0]
  {
    char* myX0 = (char*)sX[0] + wid * 4096;
    #pragma unroll
    for (int it = 0; it < 8; ++it) {
      int idx  = idxA[it] < 0 ? 0 : idxA[it];
      float4 a = *(const float4*)(X + (size_t)idx * FIN + c4 * 4);
      int rl   = it * 2 + sh;       // local row 0..15
      int byte = (rl * 256 + c4 * 8) ^ ((rl & 7) << 4);
      stbf4_pk(myX0, byte, a);
    }
  }
  __syncthreads();   // sW visible to all waves; ONLY barrier in the kernel

  for (int t = t_begin; t < t_end; ++t) {
    const int pb = (t - t_begin) & 1;
    char* myX = (char*)sX[pb] + wid * 4096;       // current tile (read; H reuse)
    char* nX  = (char*)sX[pb ^ 1] + wid * 4096;   // next tile (staged this iter)
    const int tile0 = t * BR;
    const bool do_stage = (t + 1 < t_end);

    // 1. issue index prefetch for t+2 (used as idxB next iteration)
    int idxC[8];
    {
      const int tC = (t + 2 < t_end) ? t + 2 : t;
      #pragma unroll
      for (int it = 0; it < 8; ++it)
        idxC[it] = bucket[tC * BR + wid * 16 + it * 2 + sh];
    }

    // 2. issue-early: gather loads for tile t+1 (write-late after compute)
    float4 ld[8];
    if (do_stage) {
      #pragma unroll
      for (int it = 0; it < 8; ++it) {
        int idx = idxB[it] < 0 ? 0 : idxB[it];
        ld[it]  = *(const float4*)(X + (size_t)idx * FIN + c4 * 4);
      }
    }

    // 3. epilogue inputs (coalesced)
    const int erow = tile0 + wid * 16 + lkg * 4;
    int4   idxQ4 = *(const int4*)(bucket + erow);
    float4 cQ4   = *(const float4*)(cbv + erow);
    int   idxQ[4] = {idxQ4.x, idxQ4.y, idxQ4.z, idxQ4.w};
    float cQ[4]   = {cQ4.x, cQ4.y, cQ4.z, cQ4.w};

    __builtin_amdgcn_sched_barrier(0);   // pin: loads above, compute below

    // 4. layer 1: [16 rows] x [64 h], K = 128 (A private, B shared W)
    f32x4 acc[4];
    #pragma unroll
    for (int n = 0; n < 4; ++n) acc[n] = f32x4{0.f, 0.f, 0.f, 0.f};

    const int axor = (lrow & 7) << 4;
    #pragma unroll
    for (int kc = 0; kc < 4; ++kc) {
      const int kb = (kc * 32 + lkg * 8) * 2;
      bf8_t au = lds_load16(myX, (lrow * 256 + kb) ^ axor);
      #pragma unroll
      for (int n = 0; n < 4; ++n) {
        int brow = n * 16 + lrow;
        int bx   = (brow * 256 + kb) ^ ((brow & 7) << 4);
        acc[n] = __builtin_amdgcn_mfma_f32_16x16x32_bf16(au, lds_load16(sW, bx), acc[n], 0, 0, 0);
      }
    }

    // 5. epilogue 1: H = relu(c*(acc+b)) -> bf16 into this wave's own region
    #pragma unroll
    for (int n = 0; n < 4; ++n) {
      int hcol = n * 16 + lrow;
      #pragma unroll
      for (int q = 0; q < 4; ++q) {
        int rr   = lkg * 4 + q;      // local row 0..15
        int byte = (rr * 128 + hcol * 2) ^ ((rr & 7) << 4);
        float hv = fmaxf(cQ[q] * (acc[n][q] + bfrag[n]), 0.f);
        *(unsigned short*)(myX + byte) = (unsigned short)(pk2(hv, hv) & 0xFFFFu);
      }
    }

    // 6. layer 2: [16 rows] x [32 o], K = 64
    f32x4 acc2[2];
    acc2[0] = f32x4{0.f, 0.f, 0.f, 0.f};
    acc2[1] = f32x4{0.f, 0.f, 0.f, 0.f};
    #pragma unroll
    for (int k2 = 0; k2 < 2; ++k2) {
      const int kb = (k2 * 32 + lkg * 8) * 2;
      const int ax = (lrow * 128 + kb) ^ axor;
      bf8_t a2 = lds_load16(myX, ax);
      #pragma unroll
      for (int n2 = 0; n2 < 2; ++n2)
        acc2[n2] = __builtin_amdgcn_mfma_f32_16x16x32_bf16(a2, wl[n2][k2], acc2[n2], 0, 0, 0);
    }

    // 7. epilogue 2: out = relu(acc2 + bl), scattered row stores (retire async)
    const size_t obase = (size_t)side * N_ROWS * ODIM;
    #pragma unroll
    for (int n2 = 0; n2 < 2; ++n2) {
      int col  = n2 * 16 + lrow;
      float bb = (n2 == 0) ? blv0 : blv1;
      #pragma unroll
      for (int q = 0; q < 4; ++q) {
        int idx = idxQ[q];
        if (idx >= 0)
          out[obase + (size_t)idx * ODIM + col] = fmaxf(acc2[n2][q] + bb, 0.f);
      }
    }

    __builtin_amdgcn_sched_barrier(0);   // pin: staged writes stay below compute

    // 8. write-late: convert + ds_write tile t+1 into the spare buffer
    if (do_stage) {
      #pragma unroll
      for (int it = 0; it < 8; ++it) {
        int rl   = it * 2 + sh;
        int byte = (rl * 256 + c4 * 8) ^ ((rl & 7) << 4);
        stbf4_pk(nX, byte, ld[it]);
      }
    }

    // 9. rotate index prefetch
    #pragma unroll
    for (int it = 0; it < 8; ++it) idxB[it] = idxC[it];
  }
}

extern "C" void kernel_launch(void* const* d_in, const int* in_sizes, int n_in,
                              void* d_out, int out_size, void* d_ws, size_t ws_size,
                              hipStream_t stream) {
  const float* user = (const float*)d_in[0];
  const float* item = (const float*)d_in[1];
  const int*   r    = (const int*)d_in[2];
  const float* c    = (const float*)d_in[3];
  const float* Wu   = (const float*)d_in[4];
  const float* bu   = (const float*)d_in[5];
  const float* Wv   = (const float*)d_in[6];
  const float* bv   = (const float*)d_in[7];
  const float* Wl   = (const float*)d_in[8];
  const float* bl   = (const float*)d_in[9];
  float* out = (float*)d_out;

  int*   bucket   = (int*)d_ws;              // NB
  float* cbv      = (float*)(bucket + NB);   // NB
  int*   blockcnt = (int*)(cbv + NB);        // NBH*KREL
  int*   base     = blockcnt + NBH * KREL;   // NBH*KREL
  int*   aoff     = base + NBH * KREL;       // KREL+1
  int*   cb       = aoff + KREL + 1;         // KREL+1
  int*   tsarr    = cb + KREL + 1;           // KREL+1

  hipMemsetAsync(bucket, 0xFF, (size_t)NB * sizeof(int), stream);
  hipMemsetAsync(cbv, 0, (size_t)NB * sizeof(float), stream);

  blockhist_kernel<<<NBH, 256, 0, stream>>>(r, blockcnt);
  scan_kernel<<<1, 320, 0, stream>>>(blockcnt, base, aoff, cb, tsarr);
  scatter2_kernel<<<NBH, 256, 0, stream>>>(r, c, base, bucket, cbv);
  gcn_main<<<2 * MAXCHUNK, 256, 0, stream>>>(user, item, Wu, bu, Wv, bv, Wl, bl,
                                             bucket, cbv, cb, tsarr, out);
}